// Round 1
// baseline (34.533 us; speedup 1.0000x reference)
//
#include <hip/hip_runtime.h>

// PatchShift: x (4096,4,49,32) f32 viewed as (b=8, t=8, g=64, h=4, 7, 7, c=32).
// out[b,t,g,h,i,j,c] = x[b, (t - S[i%3,j%3]) % 8, g, h, i, j, c]
// Flat: out[Bidx,h,n,c] = x[Bidx + (src_t - t)*64, h, n, c],  t = (Bidx>>6)&7.
//
// Pure gather along the t-component of the batch index; shift depends only on
// n = i*7 + j. Memory-bound: 205 MB total traffic, ~33 us roofline @6.3 TB/s.

#define NUM_B    4096
#define NUM_H    4
#define NUM_N    49
#define NUM_C4   8              // 32 floats = 8 float4
#define INNER    (NUM_H * NUM_N * NUM_C4)   // 1568 float4 per Bidx
#define TOTAL_V4 (NUM_B * INNER)            // 6,422,528

// shift[n] = table[(n/7)%3][(n%7)%3], table = [[-4,1,2],[-1,0,3],[-2,-3,4]]
__constant__ int c_shift[49] = {
    -4,  1,  2, -4,  1,  2, -4,   // i=0
    -1,  0,  3, -1,  0,  3, -1,   // i=1
    -2, -3,  4, -2, -3,  4, -2,   // i=2
    -4,  1,  2, -4,  1,  2, -4,   // i=3
    -1,  0,  3, -1,  0,  3, -1,   // i=4
    -2, -3,  4, -2, -3,  4, -2,   // i=5
    -4,  1,  2, -4,  1,  2, -4    // i=6
};

__global__ __launch_bounds__(256) void patch_shift_kernel(
    const float4* __restrict__ x, float4* __restrict__ out) {
    int i = blockIdx.x * blockDim.x + threadIdx.x;
    if (i >= TOTAL_V4) return;

    int Bidx  = i / INNER;           // [0, 4096)
    int inner = i - Bidx * INNER;    // h*392 + n*8 + c4
    int n     = (inner >> 3) % NUM_N;

    int t     = (Bidx >> 6) & 7;
    int src_t = (t - c_shift[n]) & 7;
    int srcB  = Bidx + ((src_t - t) << 6);

    out[i] = x[srcB * INNER + inner];
}

extern "C" void kernel_launch(void* const* d_in, const int* in_sizes, int n_in,
                              void* d_out, int out_size, void* d_ws, size_t ws_size,
                              hipStream_t stream) {
    const float4* x = (const float4*)d_in[0];
    float4* out = (float4*)d_out;

    int threads = 256;
    int blocks = (TOTAL_V4 + threads - 1) / threads;   // 25088
    patch_shift_kernel<<<blocks, threads, 0, stream>>>(x, out);
}